// Round 8
// baseline (582.677 us; speedup 1.0000x reference)
//
#include <hip/hip_runtime.h>
#include <hip/hip_bf16.h>

typedef __hip_bfloat16 BF;
typedef __attribute__((ext_vector_type(8))) short short8;
typedef __attribute__((ext_vector_type(4))) float f32x4;

#define DEV __device__ __forceinline__

// ---------------------------------------------------------------- helpers
DEV void gll16(const BF* g, BF* l) {
  __builtin_amdgcn_global_load_lds(
      (const __attribute__((address_space(1))) void*)g,
      (__attribute__((address_space(3))) void*)l, 16, 0, 0);
}

DEV unsigned short bfbits(float f) {
  BF b = __float2bfloat16(f);
  return *reinterpret_cast<unsigned short*>(&b);
}

// ---------------------------------------------------------------- f32 -> bf16
__global__ void f32_to_bf16_k(const float* __restrict__ in, BF* __restrict__ out, int n4) {
  int i = blockIdx.x * blockDim.x + threadIdx.x;
  if (i >= n4) return;
  const float4 v = ((const float4*)in)[i];
  ((ushort4*)out)[i] = make_ushort4(bfbits(v.x), bfbits(v.y), bfbits(v.z), bfbits(v.w));
}

// f32 -> bf16 with row padding: src rows of 4096 f32 -> dst rows of 4160 bf16
__global__ void f32_to_bf16_pad_k(const float* __restrict__ in, BF* __restrict__ out, int n4) {
  int i = blockIdx.x * blockDim.x + threadIdx.x;
  if (i >= n4) return;
  const float4 v = ((const float4*)in)[i];
  const int r = i >> 10;                 // 1024 float4 per source row (4096 f32)
  const int c = i & 1023;
  ((ushort4*)out)[r * 1040 + c] = make_ushort4(bfbits(v.x), bfbits(v.y), bfbits(v.z), bfbits(v.w));
}

// ---------------------------------------------------------------- 256^2 8-phase GEMM (B^T)
// BM=BN=256, BK=64, 8 waves (2Mx4N), per-wave 128x64 out.
// LDS: per matrix 2 bufs x [kk(2)][256][32] bf16 = 128 KiB.
// KEY (round 8): register double-buffered fragments, ds_reads issued ONE PHASE
// AHEAD, counted lgkmcnt(4/8) before MFMA (= only the just-issued reads remain
// outstanding) -> LDS drain hides under the previous MFMA cluster instead of
// serializing with it (round-7 model: 2483 MFMA + 2304 LDS cyc/K-tile ADDED).
// vmcnt ledger: <=10 loads in flight; P2 tail vmcnt(6) lands kk0(t+1) before
// P3's prefetch reads; P3 tail vmcnt(4) lands kk1(t+1). Drain-0 only last 2 tiles.

#define LDA(DST, BASE, MH, KK)                                                        \
  _Pragma("unroll") for (int m_ = 0; m_ < 4; ++m_)                                    \
      DST[m_] = *(const short8*)&(BASE)[(KK)*8192 + (wm*128 + (MH)*64 + m_*16 + l15)*32 + rd8];
#define LDB(DST, BASE, KK)                                                            \
  _Pragma("unroll") for (int n_ = 0; n_ < 4; ++n_)                                    \
      DST[n_] = *(const short8*)&(BASE)[(KK)*8192 + (wn*64 + n_*16 + l15)*32 + rd8];
#define MM(MH, AB, BB)                                                                \
  __builtin_amdgcn_s_setprio(1);                                                      \
  _Pragma("unroll") for (int m_ = 0; m_ < 4; ++m_)                                    \
    _Pragma("unroll") for (int n_ = 0; n_ < 4; ++n_)                                  \
      acc[(MH)*4 + m_][n_] =                                                          \
          __builtin_amdgcn_mfma_f32_16x16x32_bf16(AB[m_], BB[n_], acc[(MH)*4 + m_][n_], 0, 0, 0); \
  __builtin_amdgcn_s_setprio(0);
#define WAITL(N)                                                                      \
  asm volatile("s_waitcnt lgkmcnt(" #N ")" ::: "memory");                             \
  __builtin_amdgcn_sched_barrier(0);
#define WAITV(N)                                                                      \
  asm volatile("s_waitcnt vmcnt(" #N ")" ::: "memory");                               \
  __builtin_amdgcn_sched_barrier(0);
#define BAR() __builtin_amdgcn_s_barrier();
#define STG2(SRC, RST, DST) { gll16((SRC), (DST)); gll16((SRC) + (RST), (DST) + 4096); }

template <typename CT>
DEV void gemm256_body(const BF* __restrict__ A, const BF* __restrict__ Bm,
                      CT* __restrict__ C, const int M, const int N, const int K,
                      const int lda, const int ldb) {
  extern __shared__ __align__(16) BF lds[];   // A: [0,32768) elems, B: [32768,65536)
  BF* ldsA = lds;
  BF* ldsB = lds + 32768;
  const int ntl = N >> 8;
  const int mtl = M >> 8;
  int mt, nt;
  if (mtl == 16 && ntl == 32) {
    // 2-D chunked XCD raster (FETCH 507->184 MB verified round 7)
    const int x = blockIdx.x & 7;
    const int c = blockIdx.x >> 3;
    mt = ((x >> 2) << 3) + (c >> 3);
    nt = ((x & 3) << 3) + (c & 7);
  } else {
    const int cpx = gridDim.x >> 3;
    const int swzb = (blockIdx.x & 7) * cpx + (blockIdx.x >> 3);
    mt = swzb / ntl;
    nt = swzb % ntl;
  }
  const int m0 = mt << 8, n0 = nt << 8;
  const int tid = threadIdx.x, lane = tid & 63, w = tid >> 6;
  const int l15 = lane & 15, g = lane >> 4;
  const int wm = w >> 2, wn = w & 3;
  const int rd8 = (g ^ ((l15 >> 1) & 3)) << 3;
  const int trow = tid >> 2;
  const int scol = ((lane & 3) ^ ((lane >> 3) & 3)) << 3;
  const BF* aS = A + (size_t)(m0 + trow) * lda + scol;
  const BF* bS = Bm + (size_t)(n0 + trow) * ldb + scol;
  const size_t rstpA = (size_t)128 * lda;
  const size_t rstpB = (size_t)128 * ldb;
  BF* dA = ldsA + w * 512;
  BF* dB = ldsB + w * 512;
  const int NT = K >> 6;

  f32x4 acc[8][4];
#pragma unroll
  for (int m = 0; m < 8; ++m)
#pragma unroll
    for (int n = 0; n < 4; ++n) acc[m][n] = (f32x4){0.f, 0.f, 0.f, 0.f};
  short8 afA[4], afB[4], bfA[4], bfB[4];   // double-buffered fragments

  // prologue: stage t0 (kk0,kk1) + t1.kk0 = 12 loads
  STG2(aS, rstpA, dA);
  STG2(bS, rstpB, dB);
  STG2(aS + 32, rstpA, dA + 8192);
  STG2(bS + 32, rstpB, dB + 8192);
  STG2(aS + 64, rstpA, dA + 16384);
  STG2(bS + 64, rstpB, dB + 16384);
  WAITV(4)          // t0 fully landed; t1.kk0 (4 loads) still in flight
  BAR()
  LDA(afA, ldsA, 0, 0)   // prefetch P0 operands (tile 0, buf 0)
  LDB(bfA, ldsB, 0)

  for (int t = 0; t < NT; ++t) {
    const int bX = (t & 1) << 14;
    const int bY = bX ^ 16384;
    const BF* Ax = ldsA + bX;
    const BF* Bx = ldsB + bX;
    const BF* Ay = ldsA + bY;
    const BF* By = ldsB + bY;
    const int kc1 = (t + 1) << 6, kc2 = (t + 2) << 6;
    const bool s1 = (t + 1 < NT), s2 = (t + 2 < NT);

    // P0: prefetch A(mh1,kk0); MFMA(mh0,kk0) on prologue/P3-prefetched frags
    LDA(afB, Ax, 1, 0)
    if (s1) STG2(aS + kc1 + 32, rstpA, dA + bY + 8192);
    BAR()
    WAITL(4)
    MM(0, afA, bfA)
    BAR()

    // P1: prefetch A(mh0,kk1)+B(kk1); MFMA(mh1,kk0)
    LDA(afA, Ax, 0, 1)
    LDB(bfB, Bx, 1)
    if (s1) STG2(bS + kc1 + 32, rstpB, dB + bY + 8192);
    BAR()
    WAITL(8)
    MM(1, afB, bfA)
    BAR()

    // P2: prefetch A(mh1,kk1); MFMA(mh0,kk1); tail lands kk0(t+1)
    LDA(afB, Ax, 1, 1)
    if (s2) STG2(aS + kc2, rstpA, dA + bX);
    BAR()
    WAITL(4)
    MM(0, afA, bfB)
    if (s2) { WAITV(6) } else { WAITV(0) }
    BAR()

    // P3: prefetch next tile's A(mh0,kk0)+B(kk0) from buffer Y; MFMA(mh1,kk1);
    //     tail lands kk1(t+1)
    if (s1) { LDA(afA, Ay, 0, 0) LDB(bfA, By, 0) }
    if (s2) STG2(bS + kc2, rstpB, dB + bX);
    BAR()
    if (s1) { WAITL(8) } else { WAITL(0) }
    MM(1, afB, bfB)
    if (s2) { WAITV(4) } else { WAITV(0) }
    BAR()
  }

#pragma unroll
  for (int mi = 0; mi < 8; ++mi) {
    const int gr = m0 + wm * 128 + mi * 16 + g * 4;
#pragma unroll
    for (int n = 0; n < 4; ++n) {
      const int gc = n0 + wn * 64 + n * 16 + l15;
#pragma unroll
      for (int r = 0; r < 4; ++r) {
        const float v = acc[mi][n][r];
        if constexpr (sizeof(CT) == 2)
          C[(size_t)(gr + r) * N + gc] = __float2bfloat16(v);
        else
          C[(size_t)(gr + r) * N + gc] = v;
      }
    }
  }
}

// distinct names so rocprof separates the two GEMMs
__global__ __launch_bounds__(512, 2) void gemm_qkv(const BF* __restrict__ A,
                                                   const BF* __restrict__ Bm,
                                                   BF* __restrict__ C,
                                                   int M, int N, int K, int lda, int ldb) {
  gemm256_body<BF>(A, Bm, C, M, N, K, lda, ldb);
}
__global__ __launch_bounds__(512, 2) void gemm_out(const BF* __restrict__ A,
                                                   const BF* __restrict__ Bm,
                                                   float* __restrict__ C,
                                                   int M, int N, int K, int lda, int ldb) {
  gemm256_body<float>(A, Bm, C, M, N, K, lda, ldb);
}

// ---------------------------------------------------------------- RMSNorm + RoPE
__global__ __launch_bounds__(256) void rmsrope(const BF* __restrict__ C1,
                                               BF* __restrict__ Qo, BF* __restrict__ Ko,
                                               const float* __restrict__ cosl,
                                               const float* __restrict__ sinl,
                                               const float* __restrict__ qw,
                                               const float* __restrict__ kw) {
  const int gwid = (blockIdx.x * 256 + threadIdx.x) >> 6;
  const int lane = threadIdx.x & 63;
  const int slot = gwid % 24;
  const int bt = gwid / 24;            // b*2048 + t
  const int b = bt >> 11, t = bt & 2047;
  const BF* src;
  BF* dst;
  const float* wgt;
  if (slot < 16) {
    src = C1 + (size_t)bt * 8192 + slot * 256;
    dst = Qo + ((size_t)(b * 16 + slot) * 2048 + t) * 256;
    wgt = qw;
  } else {
    const int kv = slot - 16;
    src = C1 + (size_t)bt * 8192 + 4096 + kv * 256;
    dst = Ko + ((size_t)(b * 8 + kv) * 2048 + t) * 256;
    wgt = kw;
  }
  const int d2 = lane * 2;
  const ushort2 lo = *(const ushort2*)((const unsigned short*)src + d2);
  const ushort2 hi = *(const ushort2*)((const unsigned short*)src + 128 + d2);
  float x0 = __bfloat162float(*(const BF*)&lo.x);
  float x1 = __bfloat162float(*(const BF*)&lo.y);
  float x2 = __bfloat162float(*(const BF*)&hi.x);
  float x3 = __bfloat162float(*(const BF*)&hi.y);
  float ss = x0 * x0 + x1 * x1 + x2 * x2 + x3 * x3;
#pragma unroll
  for (int mm = 32; mm >= 1; mm >>= 1) ss += __shfl_xor(ss, mm);
  const float nrm = rsqrtf(ss * (1.f / 256.f) + 1e-6f);
  const float2 wlo = *(const float2*)(wgt + d2);
  const float2 whi = *(const float2*)(wgt + 128 + d2);
  x0 *= nrm * wlo.x;
  x1 *= nrm * wlo.y;
  x2 *= nrm * whi.x;
  x3 *= nrm * whi.y;
  const float2 c = *(const float2*)(cosl + t * 128 + d2);
  const float2 s = *(const float2*)(sinl + t * 128 + d2);
  ushort2 olo, ohi;
  olo.x = bfbits(x0 * c.x - x2 * s.x);
  olo.y = bfbits(x1 * c.y - x3 * s.y);
  ohi.x = bfbits(x2 * c.x + x0 * s.x);
  ohi.y = bfbits(x3 * c.y + x1 * s.y);
  *(ushort2*)((unsigned short*)dst + d2) = olo;
  *(ushort2*)((unsigned short*)dst + 128 + d2) = ohi;
}

// ---------------------------------------------------------------- V transpose
__global__ void vtrans(const BF* __restrict__ C1, BF* __restrict__ Vt) {
  __shared__ BF tile[32][33];
  const int bz = blockIdx.z;  // b*8+kv
  const int tt = blockIdx.x;  // t tile
  const int dt = blockIdx.y;  // d tile
  const int x = threadIdx.x, y0 = threadIdx.y;
  const int b = bz >> 3, kv = bz & 7;
#pragma unroll
  for (int yy = y0; yy < 32; yy += 8) {
    const int t = tt * 32 + yy, d = dt * 32 + x;
    tile[yy][x] = C1[((size_t)(b * 2048 + t)) * 8192 + 6144 + kv * 256 + d];
  }
  __syncthreads();
#pragma unroll
  for (int yy = y0; yy < 32; yy += 8) {
    const int d = dt * 32 + yy, t = tt * 32 + x;
    Vt[((size_t)bz * 256 + d) * 2048 + t] = tile[x][yy];
  }
}

// ---------------------------------------------------------------- flash attention
// O row stride 4160
__global__ __launch_bounds__(256, 2) void attn_fwd(const BF* __restrict__ Q,
                                                   const BF* __restrict__ K,
                                                   const BF* __restrict__ Vt,
                                                   BF* __restrict__ O) {
  __shared__ __align__(16) BF Ks[64 * 256];
  __shared__ __align__(16) BF Vs[256 * 64];
  __shared__ __align__(16) BF Ps[4][1024];
  const int tid = threadIdx.x;
  const int lane = tid & 63;
  const int w = tid >> 6;
  const int l15 = lane & 15;
  const int g = lane >> 4;
  const int qt = blockIdx.x;
  const int bh = blockIdx.y;
  const int b = bh >> 4, h = bh & 15;
  const int kvh = h >> 1;
  const int q0 = qt << 6;
  const BF* Qb = Q + ((size_t)bh * 2048 + q0) * 256;
  const BF* Kb = K + (size_t)(b * 8 + kvh) * 2048 * 256;
  const BF* Vb = Vt + (size_t)(b * 8 + kvh) * 256 * 2048;

  short8 qf[8];
  {
    const BF* qr = Qb + (w * 16 + l15) * 256 + g * 8;
#pragma unroll
    for (int kk = 0; kk < 8; ++kk) qf[kk] = *(const short8*)(qr + kk * 32);
  }
  f32x4 oacc[16];
#pragma unroll
  for (int i = 0; i < 16; ++i) oacc[i] = (f32x4){0.f, 0.f, 0.f, 0.f};
  float m_r[4] = {-1e30f, -1e30f, -1e30f, -1e30f};
  float l_r[4] = {0.f, 0.f, 0.f, 0.f};

  const int kt_lo = (q0 > 1023) ? ((q0 - 1023) >> 6) : 0;
  for (int kt = kt_lo; kt <= qt; ++kt) {
    const int tk = kt << 6;
#pragma unroll
    for (int i = 0; i < 8; ++i) {
      const int li = w * 8 + i;
      {
        const int row = li * 2 + (lane >> 5);
        const int ch = lane & 31;
        gll16(Kb + (size_t)(tk + row) * 256 + ((ch ^ (row & 7)) << 3), Ks + li * 512);
      }
      {
        const int row = li * 8 + (lane >> 3);
        const int ch = lane & 7;
        gll16(Vb + (size_t)row * 2048 + tk + ((ch ^ (row & 7)) << 3), Vs + li * 512);
      }
    }
    __syncthreads();

    f32x4 sa[4];
#pragma unroll
    for (int i2 = 0; i2 < 4; ++i2) sa[i2] = (f32x4){0.f, 0.f, 0.f, 0.f};
#pragma unroll
    for (int kk = 0; kk < 8; ++kk) {
      const int d = kk * 32 + g * 8;
#pragma unroll
      for (int blk = 0; blk < 4; ++blk) {
        const int row = blk * 16 + l15;
        const short8 kf = *(const short8*)&Ks[row * 256 + (d ^ ((row & 7) << 3))];
        sa[blk] = __builtin_amdgcn_mfma_f32_16x16x32_bf16(qf[kk], kf, sa[blk], 0, 0, 0);
      }
    }

    float al4[4];
#pragma unroll
    for (int r = 0; r < 4; ++r) {
      const int qi = q0 + w * 16 + g * 4 + r;
      float pv[4];
      float tmax = -1e30f;
#pragma unroll
      for (int blk = 0; blk < 4; ++blk) {
        const int ki = tk + blk * 16 + l15;
        float sv = sa[blk][r] * 0.0625f;
        const bool ok = (ki <= qi) && (qi - ki < 1024);
        sv = ok ? sv : -1e30f;
        pv[blk] = sv;
        tmax = fmaxf(tmax, sv);
      }
#pragma unroll
      for (int mm = 1; mm < 16; mm <<= 1) tmax = fmaxf(tmax, __shfl_xor(tmax, mm));
      const float mn = fmaxf(m_r[r], tmax);
      const float alpha = __expf(m_r[r] - mn);
      float tsum = 0.f;
#pragma unroll
      for (int blk = 0; blk < 4; ++blk) {
        const float p = __expf(pv[blk] - mn);
        pv[blk] = p;
        tsum += p;
      }
#pragma unroll
      for (int mm = 1; mm < 16; mm <<= 1) tsum += __shfl_xor(tsum, mm);
      l_r[r] = l_r[r] * alpha + tsum;
      m_r[r] = mn;
      al4[r] = alpha;
      const int prow = g * 4 + r;
#pragma unroll
      for (int blk = 0; blk < 4; ++blk) {
        const int col = blk * 16 + l15;
        Ps[w][prow * 64 + (col ^ ((prow & 7) << 3))] = __float2bfloat16(pv[blk]);
      }
    }
#pragma unroll
    for (int db = 0; db < 16; ++db)
#pragma unroll
      for (int r = 0; r < 4; ++r) oacc[db][r] *= al4[r];

#pragma unroll
    for (int kk2 = 0; kk2 < 2; ++kk2) {
      const int k8 = kk2 * 32 + g * 8;
      const short8 pf = *(const short8*)&Ps[w][l15 * 64 + (k8 ^ ((l15 & 7) << 3))];
#pragma unroll
      for (int db = 0; db < 16; ++db) {
        const int vrow = db * 16 + l15;
        const short8 vf = *(const short8*)&Vs[vrow * 64 + (k8 ^ ((vrow & 7) << 3))];
        oacc[db] = __builtin_amdgcn_mfma_f32_16x16x32_bf16(pf, vf, oacc[db], 0, 0, 0);
      }
    }
    __syncthreads();
  }

#pragma unroll
  for (int r = 0; r < 4; ++r) l_r[r] = 1.f / l_r[r];
  const size_t orow0 = (size_t)(b * 2048 + q0 + w * 16 + g * 4);
#pragma unroll
  for (int r = 0; r < 4; ++r) {
    BF* op = O + (orow0 + r) * 4160 + h * 256 + l15;
#pragma unroll
    for (int db = 0; db < 16; ++db) op[db * 16] = __float2bfloat16(oacc[db][r] * l_r[r]);
  }
}

// ---------------------------------------------------------------- launcher
extern "C" void kernel_launch(void* const* d_in, const int* in_sizes, int n_in,
                              void* d_out, int out_size, void* d_ws, size_t ws_size,
                              hipStream_t stream) {
  (void)in_sizes; (void)n_in; (void)out_size;
  const float* x    = (const float*)d_in[0];
  const float* cosl = (const float*)d_in[3];   // reference uses LOCAL tables for q and k
  const float* sinl = (const float*)d_in[4];
  const float* wq   = (const float*)d_in[6];
  const float* wk   = (const float*)d_in[7];
  const float* wv   = (const float*)d_in[8];
  const float* wo   = (const float*)d_in[9];
  const float* qw   = (const float*)d_in[10];
  const float* kw   = (const float*)d_in[11];
  float* out = (float*)d_out;
  char* ws = (char*)d_ws;
  if (ws_size < 161480704ull) return;

  BF* Wqkv = (BF*)(ws + 0);
  BF* Xbf  = (BF*)(ws + 62914560);
  BF* C1   = (BF*)(ws + 94371840);
  BF* Qb   = (BF*)(ws + 0);            // alias (Wqkv dead after GEMM1)
  BF* Kb   = (BF*)(ws + 33554432);
  BF* Vt   = (BF*)(ws + 62914560);     // alias (Xbf dead after GEMM1)
  BF* AO   = (BF*)(ws + 94371840);     // alias (C1 dead after vtrans), rows padded to 4160
  BF* Wo   = (BF*)(ws + 128450560);    // rows padded to 4160

  hipFuncSetAttribute(reinterpret_cast<const void*>(gemm_qkv),
                      hipFuncAttributeMaxDynamicSharedMemorySize, 131072);
  hipFuncSetAttribute(reinterpret_cast<const void*>(gemm_out),
                      hipFuncAttributeMaxDynamicSharedMemorySize, 131072);

  auto cvt = [&](const float* src, BF* dst, int n) {
    const int n4 = n >> 2;
    f32_to_bf16_k<<<(n4 + 255) / 256, 256, 0, stream>>>(src, dst, n4);
  };
  cvt(x,  Xbf, 4096 * 3840);
  cvt(wq, Wqkv, 4096 * 3840);
  cvt(wk, Wqkv + 4096 * 3840, 2048 * 3840);
  cvt(wv, Wqkv + 6144 * 3840, 2048 * 3840);

  gemm_qkv<<<512, 512, 131072, stream>>>(Xbf, Wqkv, C1, 4096, 8192, 3840, 3840, 3840);
  rmsrope<<<24576, 256, 0, stream>>>(C1, Qb, Kb, cosl, sinl, qw, kw);
  vtrans<<<dim3(64, 8, 16), dim3(32, 8), 0, stream>>>(C1, Vt);
  {
    const int n4 = (3840 * 4096) >> 2;
    f32_to_bf16_pad_k<<<(n4 + 255) / 256, 256, 0, stream>>>(wo, Wo, n4);
  }
  attn_fwd<<<dim3(32, 32), 256, 0, stream>>>(Qb, Kb, Vt, AO);
  gemm_out<<<240, 512, 131072, stream>>>(AO, Wo, out, 4096, 3840, 4096, 4160, 4160);
}

// Round 9
// 567.460 us; speedup vs baseline: 1.0268x; 1.0268x over previous
//
#include <hip/hip_runtime.h>
#include <hip/hip_bf16.h>

typedef __hip_bfloat16 BF;
typedef __attribute__((ext_vector_type(8))) short short8;
typedef __attribute__((ext_vector_type(4))) float f32x4;

#define DEV __device__ __forceinline__

// ---------------------------------------------------------------- helpers
DEV void gll16(const BF* g, BF* l) {
  __builtin_amdgcn_global_load_lds(
      (const __attribute__((address_space(1))) void*)g,
      (__attribute__((address_space(3))) void*)l, 16, 0, 0);
}

DEV unsigned short bfbits(float f) {
  BF b = __float2bfloat16(f);
  return *reinterpret_cast<unsigned short*>(&b);
}

DEV ushort4 cvt4(const float4 v) {
  return make_ushort4(bfbits(v.x), bfbits(v.y), bfbits(v.z), bfbits(v.w));
}

// ---------------------------------------------------------------- fused f32 -> bf16 (x, wq, wk, wv)
// ranges in float4 units: x[0,3932160) wq[..7864320) wk[..9830400) wv[..11796480)
__global__ void cvt_fused(const float* __restrict__ x, const float* __restrict__ wq,
                          const float* __restrict__ wk, const float* __restrict__ wv,
                          BF* __restrict__ Xbf, BF* __restrict__ Wqkv) {
  const int stride = gridDim.x * blockDim.x;
  for (int i = blockIdx.x * blockDim.x + threadIdx.x; i < 11796480; i += stride) {
    const float* src;
    ushort4* dst;
    int off;
    if (i < 3932160)      { src = x;  off = i;           dst = (ushort4*)Xbf; }
    else if (i < 7864320) { src = wq; off = i - 3932160; dst = (ushort4*)Wqkv; }
    else if (i < 9830400) { src = wk; off = i - 7864320; dst = (ushort4*)(Wqkv + 4096 * 3840); }
    else                  { src = wv; off = i - 9830400; dst = (ushort4*)(Wqkv + 6144 * 3840); }
    dst[off] = cvt4(((const float4*)src)[off]);
  }
}

// f32 -> bf16 with row padding: src rows of 4096 f32 -> dst rows of 4160 bf16
__global__ void f32_to_bf16_pad_k(const float* __restrict__ in, BF* __restrict__ out, int n4) {
  int i = blockIdx.x * blockDim.x + threadIdx.x;
  if (i >= n4) return;
  const int r = i >> 10;
  const int c = i & 1023;
  ((ushort4*)out)[r * 1040 + c] = cvt4(((const float4*)in)[i]);
}

// ---------------------------------------------------------------- 256^2 8-phase GEMM (B^T)
// Round-7 body (best measured).  BM=BN=256, BK=64, 8 waves (2Mx4N), per-wave 128x64.
// LDS: 2 bufs x [kk(2)][256][32] per matrix = 128 KiB.  B frags read once per kk.
#define PHASE(MH, KK, READB, STAGE, TAIL)                                            \
  {                                                                                  \
    short8 af[4];                                                                    \
    const BF* Ap = Ax + (KK)*8192;                                                   \
    _Pragma("unroll") for (int m = 0; m < 4; ++m)                                    \
        af[m] = *(const short8*)&Ap[(wm*128 + (MH)*64 + m*16 + l15) * 32 + rd8];     \
    if (READB) {                                                                     \
      const BF* Bp = Bx + (KK)*8192;                                                 \
      _Pragma("unroll") for (int n = 0; n < 4; ++n)                                  \
          breg[n] = *(const short8*)&Bp[(wn*64 + n*16 + l15) * 32 + rd8];            \
    }                                                                                \
    STAGE                                                                            \
    __builtin_amdgcn_s_barrier();                                                    \
    asm volatile("s_waitcnt lgkmcnt(0)" ::: "memory");                               \
    __builtin_amdgcn_sched_barrier(0);                                               \
    __builtin_amdgcn_s_setprio(1);                                                   \
    _Pragma("unroll") for (int m = 0; m < 4; ++m)                                    \
      _Pragma("unroll") for (int n = 0; n < 4; ++n)                                  \
        acc[(MH)*4 + m][n] =                                                         \
            __builtin_amdgcn_mfma_f32_16x16x32_bf16(af[m], breg[n], acc[(MH)*4+m][n], 0, 0, 0); \
    __builtin_amdgcn_s_setprio(0);                                                   \
    TAIL                                                                             \
    __builtin_amdgcn_s_barrier();                                                    \
  }

#define STG2(SRC, RST, DST) { gll16((SRC), (DST)); gll16((SRC) + (RST), (DST) + 4096); }

template <typename CT>
DEV void gemm256_body(const BF* __restrict__ A, const BF* __restrict__ Bm,
                      CT* __restrict__ C, const int M, const int N, const int K,
                      const int lda, const int ldb) {
  extern __shared__ __align__(16) BF lds[];
  BF* ldsA = lds;
  BF* ldsB = lds + 32768;
  const int ntl = N >> 8;
  const int mtl = M >> 8;
  int mt, nt;
  if (mtl == 16 && ntl == 32) {
    // 2-D chunked XCD raster (FETCH 507->184 MB verified round 7)
    const int x = blockIdx.x & 7;
    const int c = blockIdx.x >> 3;
    mt = ((x >> 2) << 3) + (c >> 3);
    nt = ((x & 3) << 3) + (c & 7);
  } else {
    const int cpx = gridDim.x >> 3;
    const int swzb = (blockIdx.x & 7) * cpx + (blockIdx.x >> 3);
    mt = swzb / ntl;
    nt = swzb % ntl;
  }
  const int m0 = mt << 8, n0 = nt << 8;
  const int tid = threadIdx.x, lane = tid & 63, w = tid >> 6;
  const int l15 = lane & 15, g = lane >> 4;
  const int wm = w >> 2, wn = w & 3;
  const int rd8 = (g ^ ((l15 >> 1) & 3)) << 3;
  const int trow = tid >> 2;
  const int scol = ((lane & 3) ^ ((lane >> 3) & 3)) << 3;
  const BF* aS = A + (size_t)(m0 + trow) * lda + scol;
  const BF* bS = Bm + (size_t)(n0 + trow) * ldb + scol;
  const size_t rstpA = (size_t)128 * lda;
  const size_t rstpB = (size_t)128 * ldb;
  BF* dA = ldsA + w * 512;
  BF* dB = ldsB + w * 512;
  const int NT = K >> 6;

  f32x4 acc[8][4];
#pragma unroll
  for (int m = 0; m < 8; ++m)
#pragma unroll
    for (int n = 0; n < 4; ++n) acc[m][n] = (f32x4){0.f, 0.f, 0.f, 0.f};
  short8 breg[4];

  STG2(aS, rstpA, dA);
  STG2(bS, rstpB, dB);
  STG2(aS + 32, rstpA, dA + 8192);
  STG2(bS + 32, rstpB, dB + 8192);
  STG2(aS + 64, rstpA, dA + 16384);
  STG2(bS + 64, rstpB, dB + 16384);
  asm volatile("s_waitcnt vmcnt(8)" ::: "memory");
  __builtin_amdgcn_sched_barrier(0);
  __builtin_amdgcn_s_barrier();

  for (int t = 0; t < NT; ++t) {
    const int bX = (t & 1) << 14;
    const int bY = bX ^ 16384;
    const BF* Ax = ldsA + bX;
    const BF* Bx = ldsB + bX;
    const int kc1 = (t + 1) << 6, kc2 = (t + 2) << 6;
    const bool s1 = (t + 1 < NT), s2 = (t + 2 < NT);
    PHASE(0, 0, 1, if (s1) STG2(aS + kc1 + 32, rstpA, dA + bY + 8192);, )
    PHASE(1, 0, 0, if (s1) STG2(bS + kc1 + 32, rstpB, dB + bY + 8192);,
          { asm volatile("s_waitcnt vmcnt(8)" ::: "memory");
            __builtin_amdgcn_sched_barrier(0); } )
    PHASE(0, 1, 1, if (s2) STG2(aS + kc2, rstpA, dA + bX);, )
    PHASE(1, 1, 0, if (s2) STG2(bS + kc2, rstpB, dB + bX);,
          if (s2) { asm volatile("s_waitcnt vmcnt(8)" ::: "memory");
                    __builtin_amdgcn_sched_barrier(0); }
          else    { asm volatile("s_waitcnt vmcnt(0)" ::: "memory");
                    __builtin_amdgcn_sched_barrier(0); } )
  }

#pragma unroll
  for (int mi = 0; mi < 8; ++mi) {
    const int gr = m0 + wm * 128 + mi * 16 + g * 4;
#pragma unroll
    for (int n = 0; n < 4; ++n) {
      const int gc = n0 + wn * 64 + n * 16 + l15;
#pragma unroll
      for (int r = 0; r < 4; ++r) {
        const float v = acc[mi][n][r];
        if constexpr (sizeof(CT) == 2)
          C[(size_t)(gr + r) * N + gc] = __float2bfloat16(v);
        else
          C[(size_t)(gr + r) * N + gc] = v;
      }
    }
  }
}

__global__ __launch_bounds__(512, 2) void gemm_qkv(const BF* __restrict__ A,
                                                   const BF* __restrict__ Bm,
                                                   BF* __restrict__ C,
                                                   int M, int N, int K, int lda, int ldb) {
  gemm256_body<BF>(A, Bm, C, M, N, K, lda, ldb);
}
__global__ __launch_bounds__(512, 2) void gemm_out(const BF* __restrict__ A,
                                                   const BF* __restrict__ Bm,
                                                   float* __restrict__ C,
                                                   int M, int N, int K, int lda, int ldb) {
  gemm256_body<float>(A, Bm, C, M, N, K, lda, ldb);
}

// ---------------------------------------------------------------- RMSNorm + RoPE
__global__ __launch_bounds__(256) void rmsrope(const BF* __restrict__ C1,
                                               BF* __restrict__ Qo, BF* __restrict__ Ko,
                                               const float* __restrict__ cosl,
                                               const float* __restrict__ sinl,
                                               const float* __restrict__ qw,
                                               const float* __restrict__ kw) {
  const int gwid = (blockIdx.x * 256 + threadIdx.x) >> 6;
  const int lane = threadIdx.x & 63;
  const int slot = gwid % 24;
  const int bt = gwid / 24;
  const int b = bt >> 11, t = bt & 2047;
  const BF* src;
  BF* dst;
  const float* wgt;
  if (slot < 16) {
    src = C1 + (size_t)bt * 8192 + slot * 256;
    dst = Qo + ((size_t)(b * 16 + slot) * 2048 + t) * 256;
    wgt = qw;
  } else {
    const int kv = slot - 16;
    src = C1 + (size_t)bt * 8192 + 4096 + kv * 256;
    dst = Ko + ((size_t)(b * 8 + kv) * 2048 + t) * 256;
    wgt = kw;
  }
  const int d2 = lane * 2;
  const ushort2 lo = *(const ushort2*)((const unsigned short*)src + d2);
  const ushort2 hi = *(const ushort2*)((const unsigned short*)src + 128 + d2);
  float x0 = __bfloat162float(*(const BF*)&lo.x);
  float x1 = __bfloat162float(*(const BF*)&lo.y);
  float x2 = __bfloat162float(*(const BF*)&hi.x);
  float x3 = __bfloat162float(*(const BF*)&hi.y);
  float ss = x0 * x0 + x1 * x1 + x2 * x2 + x3 * x3;
#pragma unroll
  for (int mm = 32; mm >= 1; mm >>= 1) ss += __shfl_xor(ss, mm);
  const float nrm = rsqrtf(ss * (1.f / 256.f) + 1e-6f);
  const float2 wlo = *(const float2*)(wgt + d2);
  const float2 whi = *(const float2*)(wgt + 128 + d2);
  x0 *= nrm * wlo.x;
  x1 *= nrm * wlo.y;
  x2 *= nrm * whi.x;
  x3 *= nrm * whi.y;
  const float2 c = *(const float2*)(cosl + t * 128 + d2);
  const float2 s = *(const float2*)(sinl + t * 128 + d2);
  ushort2 olo, ohi;
  olo.x = bfbits(x0 * c.x - x2 * s.x);
  olo.y = bfbits(x1 * c.y - x3 * s.y);
  ohi.x = bfbits(x2 * c.x + x0 * s.x);
  ohi.y = bfbits(x3 * c.y + x1 * s.y);
  *(ushort2*)((unsigned short*)dst + d2) = olo;
  *(ushort2*)((unsigned short*)dst + 128 + d2) = ohi;
}

// ---------------------------------------------------------------- V transpose
__global__ void vtrans(const BF* __restrict__ C1, BF* __restrict__ Vt) {
  __shared__ BF tile[32][33];
  const int bz = blockIdx.z;
  const int tt = blockIdx.x;
  const int dt = blockIdx.y;
  const int x = threadIdx.x, y0 = threadIdx.y;
  const int b = bz >> 3, kv = bz & 7;
#pragma unroll
  for (int yy = y0; yy < 32; yy += 8) {
    const int t = tt * 32 + yy, d = dt * 32 + x;
    tile[yy][x] = C1[((size_t)(b * 2048 + t)) * 8192 + 6144 + kv * 256 + d];
  }
  __syncthreads();
#pragma unroll
  for (int yy = y0; yy < 32; yy += 8) {
    const int d = dt * 32 + yy, t = tt * 32 + x;
    Vt[((size_t)bz * 256 + d) * 2048 + t] = tile[x][yy];
  }
}

// ---------------------------------------------------------------- flash attention (GQA head-pair fused)
// grid (qt=32, b*KV=16), 512 threads = 8 waves.  Waves 0-3: head 2*kvh, waves 4-7:
// head 2*kvh+1 -- both heads share ONE staged K/V tile (halves staging traffic).
// Each wave: 16 q-rows x 64 keys per K-tile.  O row stride 4160.
__global__ __launch_bounds__(512, 1) void attn_fwd(const BF* __restrict__ Q,
                                                   const BF* __restrict__ K,
                                                   const BF* __restrict__ Vt,
                                                   BF* __restrict__ O) {
  __shared__ __align__(16) BF Ks[64 * 256];   // 32 KB
  __shared__ __align__(16) BF Vs[256 * 64];   // 32 KB
  __shared__ __align__(16) BF Ps[8][1024];    // 16 KB
  const int tid = threadIdx.x;
  const int lane = tid & 63;
  const int w = tid >> 6;
  const int wh = w >> 2;        // which head of the pair
  const int wq = w & 3;         // q-row group
  const int l15 = lane & 15;
  const int g = lane >> 4;
  const int qt = blockIdx.x;
  const int bp = blockIdx.y;
  const int b = bp >> 3, kvh = bp & 7;
  const int h = kvh * 2 + wh;
  const int q0 = qt << 6;
  const BF* Qb = Q + ((size_t)(b * 16 + h) * 2048 + q0) * 256;
  const BF* Kb = K + (size_t)(b * 8 + kvh) * 2048 * 256;
  const BF* Vb = Vt + (size_t)(b * 8 + kvh) * 256 * 2048;

  short8 qf[8];
  {
    const BF* qr = Qb + (wq * 16 + l15) * 256 + g * 8;
#pragma unroll
    for (int kk = 0; kk < 8; ++kk) qf[kk] = *(const short8*)(qr + kk * 32);
  }
  f32x4 oacc[16];
#pragma unroll
  for (int i = 0; i < 16; ++i) oacc[i] = (f32x4){0.f, 0.f, 0.f, 0.f};
  float m_r[4] = {-1e30f, -1e30f, -1e30f, -1e30f};
  float l_r[4] = {0.f, 0.f, 0.f, 0.f};

  const int kt_lo = (q0 > 1023) ? ((q0 - 1023) >> 6) : 0;
  for (int kt = kt_lo; kt <= qt; ++kt) {
    const int tk = kt << 6;
    // stage K [64][256] + V^T [256][64], XOR-swizzled via pre-swizzled source.
    // 8 waves x 4 chunks each (was 4 waves x 8): li = w*4+i in 0..31.
#pragma unroll
    for (int i = 0; i < 4; ++i) {
      const int li = w * 4 + i;
      {
        const int row = li * 2 + (lane >> 5);
        const int ch = lane & 31;
        gll16(Kb + (size_t)(tk + row) * 256 + ((ch ^ (row & 7)) << 3), Ks + li * 512);
      }
      {
        const int row = li * 8 + (lane >> 3);
        const int ch = lane & 7;
        gll16(Vb + (size_t)row * 2048 + tk + ((ch ^ (row & 7)) << 3), Vs + li * 512);
      }
    }
    __syncthreads();

    f32x4 sa[4];
#pragma unroll
    for (int i2 = 0; i2 < 4; ++i2) sa[i2] = (f32x4){0.f, 0.f, 0.f, 0.f};
#pragma unroll
    for (int kk = 0; kk < 8; ++kk) {
      const int d = kk * 32 + g * 8;
#pragma unroll
      for (int blk = 0; blk < 4; ++blk) {
        const int row = blk * 16 + l15;
        const short8 kf = *(const short8*)&Ks[row * 256 + (d ^ ((row & 7) << 3))];
        sa[blk] = __builtin_amdgcn_mfma_f32_16x16x32_bf16(qf[kk], kf, sa[blk], 0, 0, 0);
      }
    }

    float al4[4];
#pragma unroll
    for (int r = 0; r < 4; ++r) {
      const int qi = q0 + wq * 16 + g * 4 + r;
      float pv[4];
      float tmax = -1e30f;
#pragma unroll
      for (int blk = 0; blk < 4; ++blk) {
        const int ki = tk + blk * 16 + l15;
        float sv = sa[blk][r] * 0.0625f;
        const bool ok = (ki <= qi) && (qi - ki < 1024);
        sv = ok ? sv : -1e30f;
        pv[blk] = sv;
        tmax = fmaxf(tmax, sv);
      }
#pragma unroll
      for (int mm = 1; mm < 16; mm <<= 1) tmax = fmaxf(tmax, __shfl_xor(tmax, mm));
      const float mn = fmaxf(m_r[r], tmax);
      const float alpha = __expf(m_r[r] - mn);
      float tsum = 0.f;
#pragma unroll
      for (int blk = 0; blk < 4; ++blk) {
        const float p = __expf(pv[blk] - mn);
        pv[blk] = p;
        tsum += p;
      }
#pragma unroll
      for (int mm = 1; mm < 16; mm <<= 1) tsum += __shfl_xor(tsum, mm);
      l_r[r] = l_r[r] * alpha + tsum;
      m_r[r] = mn;
      al4[r] = alpha;
      const int prow = g * 4 + r;
#pragma unroll
      for (int blk = 0; blk < 4; ++blk) {
        const int col = blk * 16 + l15;
        Ps[w][prow * 64 + (col ^ ((prow & 7) << 3))] = __float2bfloat16(pv[blk]);
      }
    }
#pragma unroll
    for (int db = 0; db < 16; ++db)
#pragma unroll
      for (int r = 0; r < 4; ++r) oacc[db][r] *= al4[r];

#pragma unroll
    for (int kk2 = 0; kk2 < 2; ++kk2) {
      const int k8 = kk2 * 32 + g * 8;
      const short8 pf = *(const short8*)&Ps[w][l15 * 64 + (k8 ^ ((l15 & 7) << 3))];
#pragma unroll
      for (int db = 0; db < 16; ++db) {
        const int vrow = db * 16 + l15;
        const short8 vf = *(const short8*)&Vs[vrow * 64 + (k8 ^ ((vrow & 7) << 3))];
        oacc[db] = __builtin_amdgcn_mfma_f32_16x16x32_bf16(pf, vf, oacc[db], 0, 0, 0);
      }
    }
    __syncthreads();
  }

#pragma unroll
  for (int r = 0; r < 4; ++r) l_r[r] = 1.f / l_r[r];
  const size_t orow0 = (size_t)(b * 2048 + q0 + wq * 16 + g * 4);
#pragma unroll
  for (int r = 0; r < 4; ++r) {
    BF* op = O + (orow0 + r) * 4160 + h * 256 + l15;
#pragma unroll
    for (int db = 0; db < 16; ++db) op[db * 16] = __float2bfloat16(oacc[db][r] * l_r[r]);
  }
}

// ---------------------------------------------------------------- launcher
// ws layout (bytes), lifetimes verified disjoint per step:
//   [0        , 62914560 )  Wqkv bf16          -> after GEMM1: Qb (33554432) + Kb@33554432 (16777216)
//   [62914560 , 94371840 )  Xbf bf16 (31457280) -> after GEMM1: Vt (16777216)
//   [94371840 , 161480704)  C1 bf16 (67108864)  -> after vtrans: AO padded (34078720) + Wo padded @128450560 (31948800)
extern "C" void kernel_launch(void* const* d_in, const int* in_sizes, int n_in,
                              void* d_out, int out_size, void* d_ws, size_t ws_size,
                              hipStream_t stream) {
  (void)in_sizes; (void)n_in; (void)out_size;
  const float* x    = (const float*)d_in[0];
  const float* cosl = (const float*)d_in[3];   // reference uses LOCAL tables for q and k
  const float* sinl = (const float*)d_in[4];
  const float* wq   = (const float*)d_in[6];
  const float* wk   = (const float*)d_in[7];
  const float* wv   = (const float*)d_in[8];
  const float* wo   = (const float*)d_in[9];
  const float* qw   = (const float*)d_in[10];
  const float* kw   = (const float*)d_in[11];
  float* out = (float*)d_out;
  char* ws = (char*)d_ws;
  if (ws_size < 161480704ull) return;

  BF* Wqkv = (BF*)(ws + 0);
  BF* Xbf  = (BF*)(ws + 62914560);
  BF* C1   = (BF*)(ws + 94371840);
  BF* Qb   = (BF*)(ws + 0);            // alias (Wqkv dead after GEMM1)
  BF* Kb   = (BF*)(ws + 33554432);
  BF* Vt   = (BF*)(ws + 62914560);     // alias (Xbf dead after GEMM1)
  BF* AO   = (BF*)(ws + 94371840);     // alias (C1 dead after vtrans), rows padded to 4160
  BF* Wo   = (BF*)(ws + 128450560);    // rows padded to 4160

  hipFuncSetAttribute(reinterpret_cast<const void*>(gemm_qkv),
                      hipFuncAttributeMaxDynamicSharedMemorySize, 131072);
  hipFuncSetAttribute(reinterpret_cast<const void*>(gemm_out),
                      hipFuncAttributeMaxDynamicSharedMemorySize, 131072);

  cvt_fused<<<2048, 256, 0, stream>>>(x, wq, wk, wv, Xbf, Wqkv);

  gemm_qkv<<<512, 512, 131072, stream>>>(Xbf, Wqkv, C1, 4096, 8192, 3840, 3840, 3840);
  rmsrope<<<24576, 256, 0, stream>>>(C1, Qb, Kb, cosl, sinl, qw, kw);
  vtrans<<<dim3(64, 8, 16), dim3(32, 8), 0, stream>>>(C1, Vt);
  {
    const int n4 = (3840 * 4096) >> 2;
    f32_to_bf16_pad_k<<<(n4 + 255) / 256, 256, 0, stream>>>(wo, Wo, n4);
  }
  attn_fwd<<<dim3(32, 16), 512, 0, stream>>>(Qb, Kb, Vt, AO);
  gemm_out<<<240, 512, 131072, stream>>>(AO, Wo, out, 4096, 3840, 4096, 4160, 4160);
}